// Round 1
// 142.380 us; speedup vs baseline: 1.0396x; 1.0396x over previous
//
#include <hip/hip_runtime.h>

#define N 8192
#define M 4
#define L 256
#define THREADS 256
#define ROWS 4
#define MAINBLK (N / ROWS)           // 2048 blocks, uniform work
#define PREPBLK 40                   // 40*256 = 10240 float4 of E exactly

// ws layout (floats)
#define WS_E 0                       // [5][N]  exp(hazards), stream-major
#define WS_TC (5 * N)                // [N]     compact times
#define WS_PART (6 * N)              // [8][MAINBLK] partials:
                                     //   0..4 cox streams, 5 kj, 6 km, 7 event-sum

__device__ __forceinline__ float waveSum(float v) {
#pragma unroll
    for (int off = 32; off > 0; off >>= 1) v += __shfl_down(v, off, 64);
    return v;
}

__device__ __forceinline__ float4 exp4(float4 h) {
    return make_float4(__expf(h.x), __expf(h.y), __expf(h.z), __expf(h.w));
}

__device__ __forceinline__ float kl4(float4 l, float4 s) {
    float k;
    k  = 0.5f * (s.x * s.x + l.x * l.x) - __logf(s.x) - 0.5f;
    k += 0.5f * (s.y * s.y + l.y * l.y) - __logf(s.y) - 0.5f;
    k += 0.5f * (s.z * s.z + l.z * l.z) - __logf(s.z) - 0.5f;
    k += 0.5f * (s.w * s.w + l.w * l.w) - __logf(s.w) - 0.5f;
    return k;
}

// ---------------- prep: exp table + compact times ----------------
__global__ __launch_bounds__(THREADS) void prep_kernel(
    const float* __restrict__ jlh, const float* __restrict__ mlh,
    const float* __restrict__ target, float* __restrict__ ws)
{
    const int idx = blockIdx.x * THREADS + threadIdx.x;  // float4 index, [0,10240)
    float4* E4 = (float4*)(ws + WS_E);
    const float4* jl4 = (const float4*)jlh;
    const float4* ml4 = (const float4*)mlh;

    // E[s][q]: s = idx>>11, q = idx&2047 (2048 f4 per stream)
    {
        const int s = idx >> 11, q = idx & 2047;
        const float4 h = (s == 0) ? jl4[q] : ml4[(s - 1) * 2048 + q];
        E4[idx] = exp4(h);
    }
    // compact times: tc[i] = target[2i]
    if (idx < 2048) {
        const float4* tg4 = (const float4*)target;
        const float4 f1 = tg4[2 * idx];
        const float4 f2 = tg4[2 * idx + 1];
        ((float4*)(ws + WS_TC))[idx] = make_float4(f1.x, f1.z, f2.x, f2.z);
    }
}

// ---------------- main: 4 cox rows + 1/2048 of KL per block ----------------
__global__ __launch_bounds__(THREADS) void main_kernel(
    const float* __restrict__ jlh, const float* __restrict__ mlh,
    const float4* __restrict__ jloc4, const float4* __restrict__ jscale4,
    const float4* __restrict__ mloc4, const float4* __restrict__ mscale4,
    const float* __restrict__ target, float* __restrict__ ws)
{
    const int tid = threadIdx.x;
    const int b = blockIdx.x;
    const int i0 = b * ROWS;

    const float* __restrict__ tc = ws + WS_TC;
    const float4* __restrict__ tc4 = (const float4*)tc;
    const float4* __restrict__ E4 = (const float4*)(ws + WS_E);

    float t_i[ROWS];
#pragma unroll
    for (int r = 0; r < ROWS; ++r) t_i[r] = tc[i0 + r];

    float acc[ROWS][5];
#pragma unroll
    for (int r = 0; r < ROWS; ++r)
#pragma unroll
        for (int s = 0; s < 5; ++s) acc[r][s] = 0.f;

    float kj = 0.f, km = 0.f;
    const int jq = b * 256 + tid;    // joint KL f4 (exactly 1 per thread)
    const int mq = b * 1024 + tid;   // modality KL f4 base (4 per thread)

    // issue first KL loads early — latency hides under cox groups
    float4 a0 = jloc4[jq], s0 = jscale4[jq];
    float4 a1 = mloc4[mq], s1 = mscale4[mq];

#define COX(g) { \
    const int q = (g) * THREADS + tid; \
    const float4 t4 = tc4[q]; \
    const float4 e0 = E4[q]; \
    const float4 e1 = E4[2048 + q]; \
    const float4 e2 = E4[4096 + q]; \
    const float4 e3 = E4[6144 + q]; \
    const float4 e4 = E4[8192 + q]; \
    _Pragma("unroll") \
    for (int r = 0; r < ROWS; ++r) { \
        const float ti = t_i[r]; \
        const float m0 = (t4.x >= ti) ? 1.f : 0.f; \
        const float m1 = (t4.y >= ti) ? 1.f : 0.f; \
        const float m2 = (t4.z >= ti) ? 1.f : 0.f; \
        const float m3 = (t4.w >= ti) ? 1.f : 0.f; \
        acc[r][0] = fmaf(m0, e0.x, fmaf(m1, e0.y, fmaf(m2, e0.z, fmaf(m3, e0.w, acc[r][0])))); \
        acc[r][1] = fmaf(m0, e1.x, fmaf(m1, e1.y, fmaf(m2, e1.z, fmaf(m3, e1.w, acc[r][1])))); \
        acc[r][2] = fmaf(m0, e2.x, fmaf(m1, e2.y, fmaf(m2, e2.z, fmaf(m3, e2.w, acc[r][2])))); \
        acc[r][3] = fmaf(m0, e3.x, fmaf(m1, e3.y, fmaf(m2, e3.z, fmaf(m3, e3.w, acc[r][3])))); \
        acc[r][4] = fmaf(m0, e4.x, fmaf(m1, e4.y, fmaf(m2, e4.z, fmaf(m3, e4.w, acc[r][4])))); \
    } }

    COX(0); COX(1);
    kj = kl4(a0, s0);                       // joint KL
    a0 = mloc4[mq + 256]; s0 = mscale4[mq + 256];
    COX(2);
    km += kl4(a1, s1);                      // modality chunk 0
    a1 = mloc4[mq + 512]; s1 = mscale4[mq + 512];
    COX(3);
    km += kl4(a0, s0);                      // modality chunk 1
    a0 = mloc4[mq + 768]; s0 = mscale4[mq + 768];
    COX(4);
    km += kl4(a1, s1);                      // modality chunk 2
    COX(5);
    km += kl4(a0, s0);                      // modality chunk 3
    COX(6); COX(7);
#undef COX

    // ---- reductions ----
#pragma unroll
    for (int r = 0; r < ROWS; ++r)
#pragma unroll
        for (int s = 0; s < 5; ++s) acc[r][s] = waveSum(acc[r][s]);
    kj = waveSum(kj);
    km = waveSum(km);

    __shared__ float red[4][22];
    const int lane = tid & 63, wid = tid >> 6;
    if (lane == 0) {
#pragma unroll
        for (int r = 0; r < ROWS; ++r)
#pragma unroll
            for (int s = 0; s < 5; ++s) red[wid][r * 5 + s] = acc[r][s];
        red[wid][20] = kj;
        red[wid][21] = km;
    }
    __syncthreads();

    __shared__ float cr[20];
    if (tid < 20) {
        const int r = tid / 5, s = tid % 5;
        const float risk = red[0][tid] + red[1][tid] + red[2][tid] + red[3][tid];
        const float ev = target[2 * (i0 + r) + 1];
        const float h = (s == 0) ? jlh[i0 + r] : mlh[(s - 1) * N + i0 + r];
        cr[tid] = ev * (h - __logf(risk));
    } else if (tid == 20) {
        ws[WS_PART + 5 * MAINBLK + b] = red[0][20] + red[1][20] + red[2][20] + red[3][20];
    } else if (tid == 21) {
        ws[WS_PART + 6 * MAINBLK + b] = red[0][21] + red[1][21] + red[2][21] + red[3][21];
    } else if (tid == 22) {
        ws[WS_PART + 7 * MAINBLK + b] =
            target[2 * i0 + 1] + target[2 * i0 + 3] + target[2 * i0 + 5] + target[2 * i0 + 7];
    }
    __syncthreads();

    if (tid < 5) {  // per-stream sum over the 4 rows
        ws[WS_PART + tid * MAINBLK + b] = cr[tid] + cr[tid + 5] + cr[tid + 10] + cr[tid + 15];
    }
}

// ---------------- finalize: tiny, coalesced ----------------
__global__ __launch_bounds__(THREADS) void finalize_kernel(
    const float* __restrict__ ws, const float* __restrict__ alpha_p,
    const float* __restrict__ beta_p, float* __restrict__ out)
{
    const int tid = threadIdx.x;
    float v[8];
#pragma unroll
    for (int k = 0; k < 8; ++k) {
        float x = 0.f;
#pragma unroll
        for (int it = 0; it < MAINBLK / THREADS; ++it)
            x += ws[WS_PART + k * MAINBLK + it * THREADS + tid];
        v[k] = waveSum(x);
    }
    __shared__ float red[8][4];
    const int lane = tid & 63, wid = tid >> 6;
    if (lane == 0)
#pragma unroll
        for (int k = 0; k < 8; ++k) red[k][wid] = v[k];
    __syncthreads();
    if (tid == 0) {
        float t[8];
#pragma unroll
        for (int k = 0; k < 8; ++k) t[k] = red[k][0] + red[k][1] + red[k][2] + red[k][3];
        const float EV = t[7];
        const float alpha = alpha_p[0], beta = beta_p[0];
        const float cox_j = -t[0] / EV;
        const float cox_m = -(t[1] + t[2] + t[3] + t[4]) / EV;
        out[0] = cox_j + beta * (t[5] / (float)N) + alpha * (cox_m + beta * (t[6] / (float)N));
    }
}

extern "C" void kernel_launch(void* const* d_in, const int* in_sizes, int n_in,
                              void* d_out, int out_size, void* d_ws, size_t ws_size,
                              hipStream_t stream) {
    const float* jlh    = (const float*)d_in[0];  // (N,)
    const float* mlh    = (const float*)d_in[1];  // (M,N)
    const float* jloc   = (const float*)d_in[2];  // (N,L)
    const float* jscale = (const float*)d_in[3];  // (N,L)
    const float* mloc   = (const float*)d_in[4];  // (M,N,L)
    const float* mscale = (const float*)d_in[5];  // (M,N,L)
    const float* target = (const float*)d_in[6];  // (N,2)
    const float* alpha  = (const float*)d_in[7];
    const float* beta   = (const float*)d_in[8];
    float* out = (float*)d_out;
    float* ws  = (float*)d_ws;

    prep_kernel<<<PREPBLK, THREADS, 0, stream>>>(jlh, mlh, target, ws);
    main_kernel<<<MAINBLK, THREADS, 0, stream>>>(
        jlh, mlh, (const float4*)jloc, (const float4*)jscale,
        (const float4*)mloc, (const float4*)mscale, target, ws);
    finalize_kernel<<<1, THREADS, 0, stream>>>(ws, alpha, beta, out);
}